// Round 1
// baseline (5590.918 us; speedup 1.0000x reference)
//
#include <hip/hip_runtime.h>
#include <math.h>

// ESN: B=64, T=2048, I=25, R=512, O=50, alpha=0.5
// R9 = 8-group x 2-chain interleave of the proven R8 seqlock protocol.
//  - 256 blocks x 512 threads: blk = g*32 + p; g in [0,8) owns rows
//    [g*64,(g+1)*64); p in [0,32) owns batches b0=2p, b1=2p+1.
//    Peers (same p, other g) differ by multiples of 32 in blockIdx ->
//    co-XCD under the measured round-robin blk%8 mapping (same property
//    R5/R8 relied on with +-64 spacing).
//  - Two independent recurrences per block hide the seqlock round trip:
//    chain-1's matvec/reduce fills chain-0's store->load window and vice
//    versa. Wave 0 polls chain 0, wave 1 polls chain 1, concurrently.
//  - W slice halves to 64x512 (32 v2f regs). Each row is still summed as
//    32 lanes x 16 cols with the identical 5-stage DPP tree -> bitwise
//    identical h trajectory to R8; only the row->lane mapping changed.
//  - Protocol unchanged (hang-free): stores ALWAYS sc0 sc1; sticky
//    per-wave fast path (sc0 loads) with bounded watchdog falling back to
//    sc0 sc1 loads. NEW: t==0 watchdog budget 2048 (vs 64) so launch skew
//    cannot trip the sticky slow mode chip-wide (R8~R5 perf parity
//    suggests exactly that happened); still bounded -> cannot hang.
// ws usage: EXACTLY 512 KB (Hf only), layout identical to R8.

typedef float v2f __attribute__((ext_vector_type(2)));
typedef float v4f __attribute__((ext_vector_type(4)));

template<int CTRL>
__device__ __forceinline__ float dpp_add(float x) {
    int y = __builtin_amdgcn_update_dpp(0, __float_as_int(x), CTRL, 0xF, 0xF, false);
    return x + __int_as_float(y);
}
// 0xB1 quad_perm[1,0,3,2], 0x4E quad_perm[2,3,0,1], 0x124 row_ror:4,
// 0x128 row_ror:8, 0x142 row_bcast15
#define DPP_REDUCE32(v) do { v = dpp_add<0xB1>(v); v = dpp_add<0x4E>(v); \
    v = dpp_add<0x124>(v); v = dpp_add<0x128>(v); v = dpp_add<0x142>(v); } while (0)

__device__ __forceinline__ void store_ic8(float* p, float h, int tag) {
    v2f v; v[0] = h; v[1] = __int_as_float(tag);
    asm volatile("global_store_dwordx2 %0, %1, off sc0 sc1"
                 :: "v"(p), "v"(v) : "memory");
}

// 7 tagged 8B loads + wait in ONE asm block (R5/R8-proven codegen shape)
__device__ __forceinline__ void load7_l2(
    const float* p0, const float* p1, const float* p2, const float* p3,
    const float* p4, const float* p5, const float* p6,
    v2f& d0, v2f& d1, v2f& d2, v2f& d3, v2f& d4, v2f& d5, v2f& d6)
{
    asm volatile(
        "global_load_dwordx2 %0, %7, off sc0\n\t"
        "global_load_dwordx2 %1, %8, off sc0\n\t"
        "global_load_dwordx2 %2, %9, off sc0\n\t"
        "global_load_dwordx2 %3, %10, off sc0\n\t"
        "global_load_dwordx2 %4, %11, off sc0\n\t"
        "global_load_dwordx2 %5, %12, off sc0\n\t"
        "global_load_dwordx2 %6, %13, off sc0\n\t"
        "s_waitcnt vmcnt(0)"
        : "=&v"(d0), "=&v"(d1), "=&v"(d2), "=&v"(d3), "=&v"(d4), "=&v"(d5), "=&v"(d6)
        : "v"(p0), "v"(p1), "v"(p2), "v"(p3), "v"(p4), "v"(p5), "v"(p6)
        : "memory");
}
__device__ __forceinline__ void load7_ic(
    const float* p0, const float* p1, const float* p2, const float* p3,
    const float* p4, const float* p5, const float* p6,
    v2f& d0, v2f& d1, v2f& d2, v2f& d3, v2f& d4, v2f& d5, v2f& d6)
{
    asm volatile(
        "global_load_dwordx2 %0, %7, off sc0 sc1\n\t"
        "global_load_dwordx2 %1, %8, off sc0 sc1\n\t"
        "global_load_dwordx2 %2, %9, off sc0 sc1\n\t"
        "global_load_dwordx2 %3, %10, off sc0 sc1\n\t"
        "global_load_dwordx2 %4, %11, off sc0 sc1\n\t"
        "global_load_dwordx2 %5, %12, off sc0 sc1\n\t"
        "global_load_dwordx2 %6, %13, off sc0 sc1\n\t"
        "s_waitcnt vmcnt(0)"
        : "=&v"(d0), "=&v"(d1), "=&v"(d2), "=&v"(d3), "=&v"(d4), "=&v"(d5), "=&v"(d6)
        : "v"(p0), "v"(p1), "v"(p2), "v"(p3), "v"(p4), "v"(p5), "v"(p6)
        : "memory");
}

__device__ __forceinline__ int permidx(int c) {
    return (c >> 7) * 128 + (c & 31) * 4 + ((c >> 5) & 3);
}

#define TAGS_BAD (__any((__float_as_int(d0.y) != want) | (__float_as_int(d1.y) != want) | \
                        (__float_as_int(d2.y) != want) | (__float_as_int(d3.y) != want) | \
                        (__float_as_int(d4.y) != want) | (__float_as_int(d5.y) != want) | \
                        (__float_as_int(d6.y) != want)))

// One chain's matvec + reduce + finalize/publish + output-projection emit.
// Uses enclosing-scope: par, npar, want, t, ct, fin, pmyrow, myrow,
// Wreg, WoutR, hperm, ovalid, oidx, lane.
#define CHAIN_COMPUTE(c, uvar, holdvar, orowp, hfN) do {                      \
    v2f acc0 = {0.f,0.f}, acc1 = {0.f,0.f};                                   \
    float op = 0.f;                                                           \
    _Pragma("unroll")                                                         \
    for (int r = 0; r < 4; ++r) {                                             \
        v4f hv = *(const v4f*)&hperm[c][par][r*128 + ct*4];                   \
        _Pragma("unroll")                                                     \
        for (int q = 0; q < 4; ++q) {                                         \
            const float hs = hv[q];                                           \
            op = fmaf(WoutR[r*4+q], hs, op);                                  \
            v2f hh = {hs, hs};                                                \
            acc0 = __builtin_elementwise_fma(Wreg[(r*4+q)*2+0], hh, acc0);    \
            acc1 = __builtin_elementwise_fma(Wreg[(r*4+q)*2+1], hh, acc1);    \
        }                                                                     \
    }                                                                         \
    float a0 = acc0[0], a1 = acc0[1], a2 = acc1[0], a3 = acc1[1];             \
    DPP_REDUCE32(a0); DPP_REDUCE32(a1); DPP_REDUCE32(a2); DPP_REDUCE32(a3);   \
    if (fin) {                                                                \
        const int j = ct & 3;                                                 \
        float y = a0;                                                         \
        if (j == 1) y = a1;                                                   \
        if (j == 2) y = a2;                                                   \
        if (j == 3) y = a3;                                                   \
        const float z  = uvar + y;                                            \
        const float e  = __expf(2.f * z);                                     \
        const float th = 1.f - 2.f * __builtin_amdgcn_rcpf(e + 1.f);          \
        holdvar = 0.5f * holdvar + 0.5f * th;                                 \
        hperm[c][npar][pmyrow] = holdvar;                                     \
        store_ic8((hfN) + 2*myrow, holdvar, want);  /* ALWAYS sc0 sc1 */      \
    }                                                                         \
    /* filler between publish and poll: out[t-1] emit */                      \
    DPP_REDUCE32(op);                                                         \
    if (t > 0 && ovalid && ((lane & 31) == 31))                               \
        (orowp)[(size_t)(t-1)*50 + oidx] = op;                                \
} while (0)

#define U_NEXT(uvar, xrowp) do {                                              \
    const int tt = (t < 2047) ? t + 1 : 2047;                                 \
    float un = 0.f;                                                           \
    _Pragma("unroll")                                                         \
    for (int k = 0; k < 25; ++k) un = fmaf(WinR[k], (xrowp)[tt*25 + k], un);  \
    uvar = un;                                                                \
} while (0)

#define CHAIN_EPI(c, orowp) do {                                              \
    float op = 0.f;                                                           \
    _Pragma("unroll")                                                         \
    for (int r = 0; r < 4; ++r) {                                             \
        v4f hv = *(const v4f*)&hperm[c][0][r*128 + ct*4];                     \
        _Pragma("unroll")                                                     \
        for (int q = 0; q < 4; ++q) op = fmaf(WoutR[r*4+q], hv[q], op);       \
    }                                                                         \
    DPP_REDUCE32(op);                                                         \
    if (ovalid && ((lane & 31) == 31))                                        \
        (orowp)[(size_t)2047*50 + oidx] = op;                                 \
} while (0)

__global__ void __launch_bounds__(512, 2)
esn_kernel(const float* __restrict__ x, const float* __restrict__ Win,
           const float* __restrict__ W, const float* __restrict__ Wout,
           float* __restrict__ out, float* __restrict__ Hf)
{
    const int p    = blockIdx.x & 31;   // batch pair
    const int g    = blockIdx.x >> 5;   // row group 0..7 (64 rows each)
    const int b0   = 2*p, b1 = 2*p + 1;
    const int tid  = threadIdx.x;
    const int rt   = tid >> 5;          // row-tile 0..15 (4 rows each)
    const int ct   = tid & 31;          // col phase
    const int lane = tid & 63;
    const int wv   = tid >> 6;          // wave 0..7
    const int hw   = rt & 1;

    __shared__ __align__(16) float hperm[2][2][512];   // [chain][parity][R]

    // ---- W slice [64 x 512] -> 32 v2f regs
    v2f Wreg[32];
    {
        const int i0 = g*64 + rt*4;
        #pragma unroll
        for (int r = 0; r < 4; ++r)
        #pragma unroll
        for (int q = 0; q < 4; ++q) {
            const float* wp = W + (r*128 + q*32 + ct);
            #pragma unroll
            for (int pp = 0; pp < 2; ++pp) {
                v2f w;
                w[0] = wp[(size_t)(i0 + 2*pp    ) * 512];
                w[1] = wp[(size_t)(i0 + 2*pp + 1) * 512];
                Wreg[(r*4+q)*2 + pp] = w;
            }
        }
    }

    // ---- Win row for this lane's finalize row
    const int myrow  = g*64 + rt*4 + (ct & 3);
    const int pmyrow = permidx(myrow);
    float WinR[25];
    #pragma unroll
    for (int k = 0; k < 25; ++k) WinR[k] = Win[myrow*25 + k];

    // ---- Wout fragment: group g owns outputs [g*7, ...) (g=7 owns just #49)
    const int obase = g*7;
    const int ocnt  = (g == 7) ? 1 : 7;
    const int oloc  = 2*wv + hw;
    const bool ovalid = (oloc < ocnt);
    const int oidx  = obase + (ovalid ? oloc : 0);
    float WoutR[16];
    #pragma unroll
    for (int r = 0; r < 4; ++r)
    #pragma unroll
    for (int q = 0; q < 4; ++q)
        WoutR[r*4+q] = ovalid ? Wout[oidx*512 + r*128 + q*32 + ct] : 0.f;

    hperm[0][0][tid] = 0.f;             // h_0 = 0, both chains
    hperm[1][0][tid] = 0.f;
    float holdv0 = 0.f, holdv1 = 0.f;
    const bool fin = (ct >= 16) & (ct < 20);

    const float* xrow0 = x   + (size_t)b0 * 2048 * 25;
    const float* xrow1 = x   + (size_t)b1 * 2048 * 25;
    float*       orow0 = out + (size_t)b0 * 2048 * 50;
    float*       orow1 = out + (size_t)b1 * 2048 * 50;
    float* HfB0 = Hf + (size_t)b0 * 1024;   // par-0 base (pairs), layout = R8
    float* HfB1 = Hf + (size_t)b1 * 1024;

    // ---- poll geometry (waves 0/1): 7 peer slices, lane offsets, LDS slots
    const int s0=(g+1)&7, s1=(g+2)&7, s2=(g+3)&7, s3=(g+4)&7,
              s4=(g+5)&7, s5=(g+6)&7, s6=(g+7)&7;
    const int o0 = s0*128 + lane*2, o1 = s1*128 + lane*2, o2 = s2*128 + lane*2,
              o3 = s3*128 + lane*2, o4 = s4*128 + lane*2, o5 = s5*128 + lane*2,
              o6 = s6*128 + lane*2;
    const int pi0 = permidx(s0*64 + lane), pi1 = permidx(s1*64 + lane),
              pi2 = permidx(s2*64 + lane), pi3 = permidx(s3*64 + lane),
              pi4 = permidx(s4*64 + lane), pi5 = permidx(s5*64 + lane),
              pi6 = permidx(s6*64 + lane);

    bool fast = true;   // sticky fast-path flag (per polling wave)

    __syncthreads();

    // u for t=0, both chains
    float u0 = 0.f, u1 = 0.f;
    #pragma unroll
    for (int k = 0; k < 25; ++k) u0 = fmaf(WinR[k], xrow0[k], u0);
    #pragma unroll
    for (int k = 0; k < 25; ++k) u1 = fmaf(WinR[k], xrow1[k], u1);

    for (int t = 0; t < 2048; ++t) {
        const int par  = t & 1;
        const int npar = par ^ 1;
        const int want = t + 1;
        float* HfN0 = HfB0 + (size_t)npar * 65536;
        float* HfN1 = HfB1 + (size_t)npar * 65536;

        // chain 0 compute+publish; its round trip is covered by chain 1
        CHAIN_COMPUTE(0, u0, holdv0, orow0, HfN0);
        U_NEXT(u0, xrow0);
        CHAIN_COMPUTE(1, u1, holdv1, orow1, HfN1);
        U_NEXT(u1, xrow1);

        // ---- waves 0/1 poll their chain's 7 remote slices concurrently
        if (wv < 2) {
            float* HfN = wv ? HfN1 : HfN0;
            const float* q0 = HfN + o0; const float* q1 = HfN + o1;
            const float* q2 = HfN + o2; const float* q3 = HfN + o3;
            const float* q4 = HfN + o4; const float* q5 = HfN + o5;
            const float* q6 = HfN + o6;
            v2f d0, d1, d2, d3, d4, d5, d6;
            if (fast) {
                const int budget = (t == 0) ? 2048 : 64;  // t0 grace vs skew
                int tries = 0;
                do { load7_l2(q0,q1,q2,q3,q4,q5,q6,d0,d1,d2,d3,d4,d5,d6); }
                while (TAGS_BAD && ++tries < budget);
                if (TAGS_BAD) fast = false;   // sticky fallback: fast path dead
            }
            if (!fast) {
                do { load7_ic(q0,q1,q2,q3,q4,q5,q6,d0,d1,d2,d3,d4,d5,d6); }
                while (TAGS_BAD);
            }
            float* hp = &hperm[wv][npar][0];
            hp[pi0] = d0.x; hp[pi1] = d1.x; hp[pi2] = d2.x; hp[pi3] = d3.x;
            hp[pi4] = d4.x; hp[pi5] = d5.x; hp[pi6] = d6.x;
        }
        __syncthreads();   // the ONLY barrier per step
    }

    // epilogue: out[b][2047] from h_2048 (parity 0), both chains
    CHAIN_EPI(0, orow0);
    CHAIN_EPI(1, orow1);
}

extern "C" void kernel_launch(void* const* d_in, const int* in_sizes, int n_in,
                              void* d_out, int out_size, void* d_ws, size_t ws_size,
                              hipStream_t stream)
{
    (void)in_sizes; (void)n_in; (void)out_size; (void)ws_size;
    const float* x    = (const float*)d_in[0];
    const float* Win  = (const float*)d_in[1];
    const float* W    = (const float*)d_in[2];
    const float* Wout = (const float*)d_in[3];
    float* out = (float*)d_out;
    float* Hf  = (float*)d_ws;   // [2][64][512] x {h,tag} = 512 KB (same as R8)
    esn_kernel<<<dim3(256), dim3(512), 0, stream>>>(x, Win, W, Wout, out, Hf);
}

// Round 2
// 3086.556 us; speedup vs baseline: 1.8114x; 1.8114x over previous
//
#include <hip/hip_runtime.h>
#include <math.h>

// ESN: B=64, T=2048, I=25, R=512, O=50, alpha=0.5
// 256 blocks x 512 threads; block=(g,b): b=blk&63, g=blk>>6 owns rows
// [g*128,(g+1)*128). W slice [128x512] fp32 in regs. Seqlock-tagged h pairs
// {h, tag=t+1} (8B single-copy atomic), double-buffered by step parity.
// R10 = R8 byte-for-byte EXCEPT the t==0 watchdog budget: 64 -> 2048.
//  Rationale: R8's sticky fast-path watchdog (64 tries ~ 20us) is smaller
//  than launch/preamble skew across 256 blocks, so 'fast' trips to false
//  chip-wide at t=0 and every step thereafter pays the IC (~900cy) path
//  for BOTH store-visibility and load, i.e. RT ~ 3000cy dominates the
//  step (FETCH_SIZE ~310MB = polls missing L2). Peers are +-64 blocks =
//  same XCD under the measured blk%8 mapping, so sc0 L2 polling is the
//  intended steady state (~250cy granularity). The grace budget is
//  bounded (2048 tries ~ 0.3ms worst, one-time) -> cannot hang; if the
//  fast path is genuinely impossible the sticky fallback still engages.
//  - stores ALWAYS sc0 sc1 (system scope, R5-proven visible everywhere).
//  - op-DPP/orow/u_next sit between publish and first poll (R8 placement).
// ws usage: EXACTLY 512 KB (Hf only), same as passing R5/R8.

typedef float v2f __attribute__((ext_vector_type(2)));
typedef float v4f __attribute__((ext_vector_type(4)));

template<int CTRL>
__device__ __forceinline__ float dpp_add(float x) {
    int y = __builtin_amdgcn_update_dpp(0, __float_as_int(x), CTRL, 0xF, 0xF, false);
    return x + __int_as_float(y);
}
// 0xB1 quad_perm[1,0,3,2], 0x4E quad_perm[2,3,0,1], 0x124 row_ror:4,
// 0x128 row_ror:8, 0x142 row_bcast15

__device__ __forceinline__ void store_ic8(float* p, float h, int tag) {
    v2f v; v[0] = h; v[1] = __int_as_float(tag);
    asm volatile("global_store_dwordx2 %0, %1, off sc0 sc1"
                 :: "v"(p), "v"(v) : "memory");
}
// 3 tagged 16B loads + wait in ONE asm block (R5-proven codegen shape)
__device__ __forceinline__ void load3_ic(const float* p0, const float* p1,
                                         const float* p2, v4f& a, v4f& b, v4f& c) {
    asm volatile("global_load_dwordx4 %0, %3, off sc0 sc1\n\t"
                 "global_load_dwordx4 %1, %4, off sc0 sc1\n\t"
                 "global_load_dwordx4 %2, %5, off sc0 sc1\n\t"
                 "s_waitcnt vmcnt(0)"
                 : "=&v"(a), "=&v"(b), "=&v"(c)
                 : "v"(p0), "v"(p1), "v"(p2) : "memory");
}
__device__ __forceinline__ void load3_l2(const float* p0, const float* p1,
                                         const float* p2, v4f& a, v4f& b, v4f& c) {
    asm volatile("global_load_dwordx4 %0, %3, off sc0\n\t"
                 "global_load_dwordx4 %1, %4, off sc0\n\t"
                 "global_load_dwordx4 %2, %5, off sc0\n\t"
                 "s_waitcnt vmcnt(0)"
                 : "=&v"(a), "=&v"(b), "=&v"(c)
                 : "v"(p0), "v"(p1), "v"(p2) : "memory");
}

__device__ __forceinline__ int permidx(int c) {
    return (c >> 7) * 128 + (c & 31) * 4 + ((c >> 5) & 3);
}

#define TAGS_BAD (__any((__float_as_int(d0.y) != want) | (__float_as_int(d0.w) != want) | \
                        (__float_as_int(d1.y) != want) | (__float_as_int(d1.w) != want) | \
                        (__float_as_int(d2.y) != want) | (__float_as_int(d2.w) != want)))

__global__ void __launch_bounds__(512, 2)
esn_kernel(const float* __restrict__ x, const float* __restrict__ Win,
           const float* __restrict__ W, const float* __restrict__ Wout,
           float* __restrict__ out, float* __restrict__ Hf)
{
    const int b    = blockIdx.x & 63;
    const int g    = blockIdx.x >> 6;
    const int tid  = threadIdx.x;
    const int rt   = tid >> 5;      // row-tile 0..15 (8 rows each)
    const int ct   = tid & 31;      // col phase
    const int lane = tid & 63;
    const int wv   = tid >> 6;      // wave 0..7
    const int hw   = rt & 1;

    __shared__ __align__(16) float hperm[2][512];

    // ---- W slice -> registers
    v2f Wreg[64];
    {
        const int i0 = g*128 + rt*8;
        #pragma unroll
        for (int r = 0; r < 4; ++r)
        #pragma unroll
        for (int q = 0; q < 4; ++q) {
            const float* wp = W + (r*128 + q*32 + ct);
            #pragma unroll
            for (int p = 0; p < 4; ++p) {
                v2f w;
                w[0] = wp[(size_t)(i0 + 2*p    ) * 512];
                w[1] = wp[(size_t)(i0 + 2*p + 1) * 512];
                Wreg[(r*4+q)*4 + p] = w;
            }
        }
    }

    // ---- Win row for this lane's finalize row i0+(ct&7)
    const int myrow = g*128 + rt*8 + (ct & 7);
    float WinR[25];
    #pragma unroll
    for (int k = 0; k < 25; ++k) WinR[k] = Win[myrow*25 + k];

    // ---- Wout fragment
    const int obase = g*13;
    const int ocnt  = (g == 3) ? 11 : 13;
    const int oloc  = 2*wv + hw;
    const bool ovalid = (oloc < ocnt);
    const int oidx  = obase + (ovalid ? oloc : 0);
    float WoutR[16];
    #pragma unroll
    for (int r = 0; r < 4; ++r)
    #pragma unroll
    for (int q = 0; q < 4; ++q)
        WoutR[r*4+q] = ovalid ? Wout[oidx*512 + r*128 + q*32 + ct] : 0.f;

    hperm[0][tid] = 0.f;        // h_0 = 0
    float holdv = 0.f;
    const bool fin = (ct >= 16) & (ct < 24);

    const float* xrow = x   + (size_t)b * 2048 * 25;
    float*       orow = out + (size_t)b * 2048 * 50;
    float* HfB0 = Hf + (size_t)b * 1024;              // par-0 base (pairs)
    const int s0 = (g+1)&3, s1 = (g+2)&3, s2 = (g+3)&3;

    bool fast = true;           // sticky fast-path flag (comm wave only)

    __syncthreads();

    // u for t=0
    float u = 0.f;
    #pragma unroll
    for (int k = 0; k < 25; ++k) u = fmaf(WinR[k], xrow[k], u);

    for (int t = 0; t < 2048; ++t) {
        const int par  = t & 1;
        const int npar = par ^ 1;
        const int want = t + 1;
        float* HfN = HfB0 + (size_t)npar * 64 * 1024;

        // ---- matvec on h_t + fused output-projection partial
        v2f acc0 = {0.f,0.f}, acc1 = {0.f,0.f}, acc2 = {0.f,0.f}, acc3 = {0.f,0.f};
        float op = 0.f;
        #pragma unroll
        for (int r = 0; r < 4; ++r) {
            v4f hv = *(const v4f*)&hperm[par][r*128 + ct*4];
            #pragma unroll
            for (int q = 0; q < 4; ++q) {
                const float hs = hv[q];
                op = fmaf(WoutR[r*4+q], hs, op);
                v2f hh = {hs, hs};
                acc0 = __builtin_elementwise_fma(Wreg[(r*4+q)*4+0], hh, acc0);
                acc1 = __builtin_elementwise_fma(Wreg[(r*4+q)*4+1], hh, acc1);
                acc2 = __builtin_elementwise_fma(Wreg[(r*4+q)*4+2], hh, acc2);
                acc3 = __builtin_elementwise_fma(Wreg[(r*4+q)*4+3], hh, acc3);
            }
        }

        // ---- FULL 32-lane reduce of 8 row partials (totals land in lanes 16..31)
        float ar[8] = {acc0[0],acc0[1],acc1[0],acc1[1],acc2[0],acc2[1],acc3[0],acc3[1]};
        #pragma unroll
        for (int j = 0; j < 8; ++j) {
            ar[j] = dpp_add<0xB1>(ar[j]);
            ar[j] = dpp_add<0x4E>(ar[j]);
            ar[j] = dpp_add<0x124>(ar[j]);
            ar[j] = dpp_add<0x128>(ar[j]);
            ar[j] = dpp_add<0x142>(ar[j]);
        }

        // ---- finalize rows i0+(ct&7) (lanes ct in [16,24)), publish ASAP
        if (fin) {
            const int j = ct & 7;
            float y = ar[0];
            if (j == 1) y = ar[1];
            if (j == 2) y = ar[2];
            if (j == 3) y = ar[3];
            if (j == 4) y = ar[4];
            if (j == 5) y = ar[5];
            if (j == 6) y = ar[6];
            if (j == 7) y = ar[7];
            const float z  = u + y;
            const float e  = __expf(2.f * z);
            const float th = 1.f - 2.f * __builtin_amdgcn_rcpf(e + 1.f);  // tanh
            holdv = 0.5f * holdv + 0.5f * th;
            hperm[npar][permidx(myrow)] = holdv;          // own slice via LDS
            store_ic8(&HfN[myrow*2], holdv, want);        // ALWAYS sc0 sc1
        }

        // ---- filler (delays first poll past the store's landing):
        //      out[b][t-1] projection emit + u_{t+1}
        op = dpp_add<0xB1>(op);  op = dpp_add<0x4E>(op);
        op = dpp_add<0x124>(op); op = dpp_add<0x128>(op);
        op = dpp_add<0x142>(op);
        if (t > 0 && ovalid && ((lane & 31) == 31))
            orow[(size_t)(t-1)*50 + oidx] = op;
        {
            const int tt = (t < 2047) ? t + 1 : 2047;
            float un = 0.f;
            #pragma unroll
            for (int k = 0; k < 25; ++k) un = fmaf(WinR[k], xrow[tt*25 + k], un);
            u = un;
        }

        // ---- comm wave: tagged fetch of 3 remote slices
        if (wv == 0) {
            const float* p0 = HfN + (s0*256 + lane*4);
            const float* p1 = HfN + (s1*256 + lane*4);
            const float* p2 = HfN + (s2*256 + lane*4);
            v4f d0, d1, d2;
            if (fast) {
                // t==0 grace: launch/preamble skew across 256 blocks can
                // exceed 64 tries; do not let it kill the sticky fast path.
                const int budget = (t == 0) ? 2048 : 64;
                int tries = 0;
                do { load3_l2(p0, p1, p2, d0, d1, d2); } while (TAGS_BAD && ++tries < budget);
                if (TAGS_BAD) fast = false;   // sticky fallback: fast path dead
            }
            if (!fast) {
                do { load3_ic(p0, p1, p2, d0, d1, d2); } while (TAGS_BAD);
            }
            const int c0 = s0*128 + 2*lane, c1 = s1*128 + 2*lane, c2 = s2*128 + 2*lane;
            hperm[npar][permidx(c0)]     = d0.x;
            hperm[npar][permidx(c0 + 1)] = d0.z;
            hperm[npar][permidx(c1)]     = d1.x;
            hperm[npar][permidx(c1 + 1)] = d1.z;
            hperm[npar][permidx(c2)]     = d2.x;
            hperm[npar][permidx(c2 + 1)] = d2.z;
        }
        __syncthreads();   // the ONLY barrier per step
    }

    // epilogue: out[b][2047] from h_2048 (in hperm[0])
    {
        float op = 0.f;
        #pragma unroll
        for (int r = 0; r < 4; ++r) {
            v4f hv = *(const v4f*)&hperm[0][r*128 + ct*4];
            #pragma unroll
            for (int q = 0; q < 4; ++q) op = fmaf(WoutR[r*4+q], hv[q], op);
        }
        op = dpp_add<0xB1>(op);  op = dpp_add<0x4E>(op);
        op = dpp_add<0x124>(op); op = dpp_add<0x128>(op);
        op = dpp_add<0x142>(op);
        if (ovalid && ((lane & 31) == 31))
            orow[(size_t)2047*50 + oidx] = op;
    }
}

extern "C" void kernel_launch(void* const* d_in, const int* in_sizes, int n_in,
                              void* d_out, int out_size, void* d_ws, size_t ws_size,
                              hipStream_t stream)
{
    (void)in_sizes; (void)n_in; (void)out_size; (void)ws_size;
    const float* x    = (const float*)d_in[0];
    const float* Win  = (const float*)d_in[1];
    const float* W    = (const float*)d_in[2];
    const float* Wout = (const float*)d_in[3];
    float* out = (float*)d_out;
    float* Hf  = (float*)d_ws;   // [2][64][512] x {h,tag} = 512 KB (same as R5)
    esn_kernel<<<dim3(256), dim3(512), 0, stream>>>(x, Win, W, Wout, out, Hf);
}